// Round 20
// baseline (39.150 us; speedup 1.0000x reference)
//
#include <hip/hip_runtime.h>
#include <hip/hip_bf16.h>

// DualMem fast_get_image_pred:
//   logits[b,c] = 100 * (Σ_m w_m sim_m) / sqrt(Σ_{i,j} w_i w_j G[c,i,j])
//
// Lesson ledger (20 rounds):
//  - Spill triggers: launch_bounds 2nd arg / non-256 blocks / >=48KB LDS
//    starve the allocator; local arrays passed to helpers go to scratch.
//  - R12-R18: MFMA fragment loads from row-major f32 touch 16 lines/wave-load
//    -> address-path bound, invariant under ILP/occupancy/split-K. Cost
//    scales with TOTAL loads: re-reading mem per (c,split) was 57us; reading
//    each byte once (packgram) is ~2us. Contiguous fragment-ordered loads
//    (imgP) are 8 lines and cheap.
//  - R18/R19 (verified, 78->51.5->36.2us): pack into fragment order, fuse
//    passes. Remaining waste was memP's 66MB HBM round-trip + 3-deep
//    dispatch chain => THIS round: single fused kernel per class (pack mem
//    fragments in registers, sim+gram+finish in-block); only imgP (128KB)
//    is precomputed. HBM traffic 111 -> 45.5 MB compulsory.
//  - MFMA C-layout col=lane&15, row=(lane>>4)*4+reg (verified R12/R13).
//
// Structure (2 dispatches):
//   P1 pack_img: imgP[4][32][64] bf16x8 fragments (128 KB, L2-hot).
//   K1 fused: grid(1000); each wave packs all 32 mem-ksteps in regs
//      (waves 1-3 L1/L2-hot), 2 sim chains vs imgP + 2 gram chains (A==B);
//      sims -> 3KB LDS, wave-0 gram -> 0.5KB LDS, barrier, finish.
//   Fallback (ws < 128KB): same kernel but A-fragments packed from img
//      in-loop (extra lines, still correct).

constexpr int Bn = 64;     // batch
constexpr int Cn = 1000;   // classes
constexpr int Mn = 11;     // memories per class
constexpr int Dn = 1024;   // feature dim
constexpr float BETA = 5.5f;

typedef __attribute__((ext_vector_type(8))) short bf16x8;
typedef __attribute__((ext_vector_type(4))) float f32x4;

__device__ inline short f2bf(float x) {
    union { __hip_bfloat16 h; short s; } u;
    u.h = __float2bfloat16(x);
    return u.s;
}

__device__ inline bf16x8 pack_bf16x8(const float4 a, const float4 b) {
    bf16x8 r;
    r[0] = f2bf(a.x); r[1] = f2bf(a.y); r[2] = f2bf(a.z); r[3] = f2bf(a.w);
    r[4] = f2bf(b.x); r[5] = f2bf(b.y); r[6] = f2bf(b.z); r[7] = f2bf(b.w);
    return r;
}

// ---------------- P1: imgP fragments (R18-verified) ----------------
__global__ __launch_bounds__(256) void pack_img_kernel(
    const float* __restrict__ img, bf16x8* __restrict__ imgP) {
    const int t = blockIdx.x * 256 + threadIdx.x;   // 8192 chunks
    const int l = t & 63;
    const int kstep = (t >> 6) & 31;
    const int w = t >> 11;
    const int row = w * 16 + (l & 15);
    const int kcol = kstep * 32 + (l >> 4) * 8;
    const float4 a0 = *reinterpret_cast<const float4*>(img + row * Dn + kcol);
    const float4 a1 = *reinterpret_cast<const float4*>(img + row * Dn + kcol + 4);
    imgP[t] = pack_bf16x8(a0, a1);
}

// ---------------- K1: fully fused per-class kernel ----------------
// IMGP_MODE 1: A-fragments from imgP (contiguous). 0: packed from img in-loop.
template <int IMGP_MODE>
__global__ __launch_bounds__(256) void fused_kernel(
    const float* __restrict__ img, const bf16x8* __restrict__ imgP,
    const float* __restrict__ mem, float* __restrict__ out) {
    const int c   = blockIdx.x;
    const int tid = threadIdx.x;
    const int l   = tid & 63;
    const int w   = tid >> 6;         // wave = b-tile
    const int rw  = l & 15;
    const int mrow = (rw < Mn) ? rw : 0;   // pad rows alias row 0
    const int kb   = (l >> 4) * 8;

    const float* mc = mem + (size_t)c * (Mn * Dn) + mrow * Dn + kb;
    const bf16x8* pA = imgP + (size_t)w * 2048 + l;
    const float* ic = img + (w * 16 + rw) * Dn + kb;

    // 2 sim chains + 2 gram chains, all independent
    f32x4 accS0 = {0.f, 0.f, 0.f, 0.f};
    f32x4 accS1 = {0.f, 0.f, 0.f, 0.f};
    f32x4 accG0 = {0.f, 0.f, 0.f, 0.f};
    f32x4 accG1 = {0.f, 0.f, 0.f, 0.f};

#pragma unroll
    for (int r = 0; r < 16; ++r) {
        const int k0 = (2 * r) * 32;
        const int k1 = (2 * r + 1) * 32;
        const float4 m00 = *reinterpret_cast<const float4*>(mc + k0);
        const float4 m01 = *reinterpret_cast<const float4*>(mc + k0 + 4);
        const float4 m10 = *reinterpret_cast<const float4*>(mc + k1);
        const float4 m11 = *reinterpret_cast<const float4*>(mc + k1 + 4);
        bf16x8 a0, a1;
        if (IMGP_MODE) {
            a0 = pA[(2 * r) * 64];
            a1 = pA[(2 * r + 1) * 64];
        } else {
            const float4 i00 = *reinterpret_cast<const float4*>(ic + k0);
            const float4 i01 = *reinterpret_cast<const float4*>(ic + k0 + 4);
            const float4 i10 = *reinterpret_cast<const float4*>(ic + k1);
            const float4 i11 = *reinterpret_cast<const float4*>(ic + k1 + 4);
            a0 = pack_bf16x8(i00, i01);
            a1 = pack_bf16x8(i10, i11);
        }
        const bf16x8 f0 = pack_bf16x8(m00, m01);
        const bf16x8 f1 = pack_bf16x8(m10, m11);
        accS0 = __builtin_amdgcn_mfma_f32_16x16x32_bf16(a0, f0, accS0, 0, 0, 0);
        accS1 = __builtin_amdgcn_mfma_f32_16x16x32_bf16(a1, f1, accS1, 0, 0, 0);
        accG0 = __builtin_amdgcn_mfma_f32_16x16x32_bf16(f0, f0, accG0, 0, 0, 0);
        accG1 = __builtin_amdgcn_mfma_f32_16x16x32_bf16(f1, f1, accG1, 0, 0, 0);
    }
    const f32x4 accS = accS0 + accS1;

    // C layout: col = l&15 (m), rows w*16+(l>>4)*4+{0..3} (b)
    __shared__ float redS[Bn][12];     // 3 KB
    __shared__ float redG[Mn * Mn];    // 484 B
    const int mcol = l & 15;
    const int br   = w * 16 + (l >> 4) * 4;
    if (mcol < Mn) {
        redS[br + 0][mcol] = accS[0];
        redS[br + 1][mcol] = accS[1];
        redS[br + 2][mcol] = accS[2];
        redS[br + 3][mcol] = accS[3];
    }
    // every wave computed the full gram (all 32 ksteps); wave 0's copy suffices
    if (w == 0) {
        const f32x4 g = accG0 + accG1;
        const int r0 = (l >> 4) * 4;
        if (mcol < Mn) {
            if (r0 + 0 < Mn) redG[(r0 + 0) * Mn + mcol] = g[0];
            if (r0 + 1 < Mn) redG[(r0 + 1) * Mn + mcol] = g[1];
            if (r0 + 2 < Mn) redG[(r0 + 2) * Mn + mcol] = g[2];
            if (r0 + 3 < Mn) redG[(r0 + 3) * Mn + mcol] = g[3];
        }
    }
    __syncthreads();

    // finish: one thread per b
    if (tid < Bn) {
        const int b = tid;
        float wv[Mn];
        float numer = 0.f;
#pragma unroll
        for (int m = 0; m < Mn; ++m) {
            const float s = redS[b][m];
            wv[m] = __expf(BETA * (s - 1.f));
            numer = fmaf(wv[m], s, numer);
        }
        float den2 = 0.f;
#pragma unroll
        for (int i = 0; i < Mn; ++i) {
            float row = 0.f;
#pragma unroll
            for (int j = 0; j < Mn; ++j) row = fmaf(wv[j], redG[i * Mn + j], row);
            den2 = fmaf(wv[i], row, den2);
        }
        out[b * Cn + c] = 100.f * numer / sqrtf(den2);
    }
}

extern "C" void kernel_launch(void* const* d_in, const int* in_sizes, int n_in,
                              void* d_out, int out_size, void* d_ws, size_t ws_size,
                              hipStream_t stream) {
    const float* img = (const float*)d_in[0];  // [64][1024] f32
    const float* mem = (const float*)d_in[1];  // [1000][11][1024] f32
    float* out = (float*)d_out;                // [64][1000] f32
    (void)in_sizes; (void)n_in; (void)out_size;

    constexpr size_t IMGP_B = (size_t)4 * 32 * 64 * 16;   // 128 KB

    if (ws_size >= IMGP_B) {
        bf16x8* imgP = (bf16x8*)d_ws;
        pack_img_kernel<<<dim3(32), dim3(256), 0, stream>>>(img, imgP);
        fused_kernel<1><<<dim3(Cn), dim3(256), 0, stream>>>(img, imgP, mem, out);
    } else {
        fused_kernel<0><<<dim3(Cn), dim3(256), 0, stream>>>(img, nullptr, mem, out);
    }
}

// Round 21
// 22.907 us; speedup vs baseline: 1.7091x; 1.7091x over previous
//
#include <hip/hip_runtime.h>
#include <hip/hip_bf16.h>

// DualMem fast_get_image_pred:
//   logits[b,c] = 100 * (Σ_m w_m sim_m) / sqrt(Σ_{i,j} w_i w_j G[c,i,j])
//
// Lesson ledger (21 rounds):
//  - Spill triggers: launch_bounds 2nd arg / non-256 blocks / >=48KB LDS
//    starve the allocator; local arrays passed to helpers go to scratch.
//  - R12-R20: cost function of the MFMA path = total wave-loads x lines per
//    load (~4 cyc/line empirically). Fragment-pattern f32 loads = 16 lines;
//    fragment-ordered bf16 loads = 8 contiguous. Re-reading mem per wave
//    (R20) or per split (R17) multiplies the dominant term. Ladder:
//    57us (redundant fragment reads) -> 36us (pack once, 3 dispatches) ->
//    39us (fused but 4x redundant) -> THIS: fused with K SPLIT ACROSS WAVES
//    so each mem byte is read exactly once per block, gram rides on the
//    packed register fragments, imgP loads contiguous. 192 wave-loads/block
//    vs R20's 512; memP eliminated; 2 dispatches.
//  - MFMA C-layout col=lane&15, row=(lane>>4)*4+reg (verified R12/R13).
//
// Structure (2 dispatches):
//   P1 pack_img: imgP[4][32][64] bf16x8 fragments (128 KB, L2-hot).
//   K1 fused2: grid(1000); wave w packs mem ksteps {8w..8w+7} (once),
//      gram partial (8 MFMA, A==B), sim partials vs ALL 4 b-tiles' imgP
//      (32 MFMA). LDS: redS[4][64][12] + redGp[4][64]x4 + redG[121]
//      (~16.9 KB). Two barriers, in-block finish.

constexpr int Bn = 64;     // batch
constexpr int Cn = 1000;   // classes
constexpr int Mn = 11;     // memories per class
constexpr int Dn = 1024;   // feature dim
constexpr float BETA = 5.5f;

typedef __attribute__((ext_vector_type(8))) short bf16x8;
typedef __attribute__((ext_vector_type(4))) float f32x4;

__device__ inline short f2bf(float x) {
    union { __hip_bfloat16 h; short s; } u;
    u.h = __float2bfloat16(x);
    return u.s;
}

__device__ inline bf16x8 pack_bf16x8(const float4 a, const float4 b) {
    bf16x8 r;
    r[0] = f2bf(a.x); r[1] = f2bf(a.y); r[2] = f2bf(a.z); r[3] = f2bf(a.w);
    r[4] = f2bf(b.x); r[5] = f2bf(b.y); r[6] = f2bf(b.z); r[7] = f2bf(b.w);
    return r;
}

// ---------------- P1: imgP fragments (R18-verified) ----------------
__global__ __launch_bounds__(256) void pack_img_kernel(
    const float* __restrict__ img, bf16x8* __restrict__ imgP) {
    const int t = blockIdx.x * 256 + threadIdx.x;   // 8192 chunks
    const int l = t & 63;
    const int kstep = (t >> 6) & 31;
    const int w = t >> 11;
    const int row = w * 16 + (l & 15);
    const int kcol = kstep * 32 + (l >> 4) * 8;
    const float4 a0 = *reinterpret_cast<const float4*>(img + row * Dn + kcol);
    const float4 a1 = *reinterpret_cast<const float4*>(img + row * Dn + kcol + 4);
    imgP[t] = pack_bf16x8(a0, a1);
}

// ---------------- K1: fused, K split across waves ----------------
// IMGP_MODE 1: A-fragments from imgP (contiguous). 0: packed from img in-loop.
template <int IMGP_MODE>
__global__ __launch_bounds__(256) void fused2_kernel(
    const float* __restrict__ img, const bf16x8* __restrict__ imgP,
    const float* __restrict__ mem, float* __restrict__ out) {
    __shared__ float redS[4][Bn][12];   // per-wave partial sims (12 KB)
    __shared__ f32x4 redGp[4][64];      // per-wave gram partials (4 KB)
    __shared__ float redG[Mn * Mn];     // reduced gram (484 B)

    const int c   = blockIdx.x;
    const int tid = threadIdx.x;
    const int l   = tid & 63;
    const int w   = tid >> 6;          // wave owns ksteps {8w..8w+7}
    const int rw  = l & 15;
    const int mrow = (rw < Mn) ? rw : 0;   // pad rows alias row 0
    const int kb   = (l >> 4) * 8;

    const float* mc = mem + (size_t)c * (Mn * Dn) + mrow * Dn + kb;

    f32x4 accS0 = {0.f, 0.f, 0.f, 0.f};   // b-tile 0 (b 0..15)
    f32x4 accS1 = {0.f, 0.f, 0.f, 0.f};   // b-tile 1
    f32x4 accS2 = {0.f, 0.f, 0.f, 0.f};   // b-tile 2
    f32x4 accS3 = {0.f, 0.f, 0.f, 0.f};   // b-tile 3
    f32x4 accG  = {0.f, 0.f, 0.f, 0.f};   // gram partial

#pragma unroll
    for (int j = 0; j < 8; ++j) {
        const int kstep = 8 * w + j;
        // pack this kstep's mem fragment ONCE (each mem byte read once/block)
        const float4 m0 = *reinterpret_cast<const float4*>(mc + kstep * 32);
        const float4 m1 = *reinterpret_cast<const float4*>(mc + kstep * 32 + 4);
        const bf16x8 f = pack_bf16x8(m0, m1);
        accG = __builtin_amdgcn_mfma_f32_16x16x32_bf16(f, f, accG, 0, 0, 0);
        // A fragments for all 4 b-tiles at this kstep
        bf16x8 a0, a1, a2, a3;
        if (IMGP_MODE) {
            const bf16x8* p = imgP + kstep * 64 + l;
            a0 = p[0];
            a1 = p[2048];
            a2 = p[4096];
            a3 = p[6144];
        } else {
            const float* ic = img + rw * Dn + kstep * 32 + kb;
            const float4 i00 = *reinterpret_cast<const float4*>(ic);
            const float4 i01 = *reinterpret_cast<const float4*>(ic + 4);
            const float4 i10 = *reinterpret_cast<const float4*>(ic + 16 * Dn);
            const float4 i11 = *reinterpret_cast<const float4*>(ic + 16 * Dn + 4);
            const float4 i20 = *reinterpret_cast<const float4*>(ic + 32 * Dn);
            const float4 i21 = *reinterpret_cast<const float4*>(ic + 32 * Dn + 4);
            const float4 i30 = *reinterpret_cast<const float4*>(ic + 48 * Dn);
            const float4 i31 = *reinterpret_cast<const float4*>(ic + 48 * Dn + 4);
            a0 = pack_bf16x8(i00, i01);
            a1 = pack_bf16x8(i10, i11);
            a2 = pack_bf16x8(i20, i21);
            a3 = pack_bf16x8(i30, i31);
        }
        accS0 = __builtin_amdgcn_mfma_f32_16x16x32_bf16(a0, f, accS0, 0, 0, 0);
        accS1 = __builtin_amdgcn_mfma_f32_16x16x32_bf16(a1, f, accS1, 0, 0, 0);
        accS2 = __builtin_amdgcn_mfma_f32_16x16x32_bf16(a2, f, accS2, 0, 0, 0);
        accS3 = __builtin_amdgcn_mfma_f32_16x16x32_bf16(a3, f, accS3, 0, 0, 0);
    }

    // stash partials: C layout col=l&15 (m), row=(l>>4)*4+reg (b within tile)
    const int mcol = l & 15;
    const int r0   = (l >> 4) * 4;
    if (mcol < Mn) {
        redS[w][ 0 + r0 + 0][mcol] = accS0[0];
        redS[w][ 0 + r0 + 1][mcol] = accS0[1];
        redS[w][ 0 + r0 + 2][mcol] = accS0[2];
        redS[w][ 0 + r0 + 3][mcol] = accS0[3];
        redS[w][16 + r0 + 0][mcol] = accS1[0];
        redS[w][16 + r0 + 1][mcol] = accS1[1];
        redS[w][16 + r0 + 2][mcol] = accS1[2];
        redS[w][16 + r0 + 3][mcol] = accS1[3];
        redS[w][32 + r0 + 0][mcol] = accS2[0];
        redS[w][32 + r0 + 1][mcol] = accS2[1];
        redS[w][32 + r0 + 2][mcol] = accS2[2];
        redS[w][32 + r0 + 3][mcol] = accS2[3];
        redS[w][48 + r0 + 0][mcol] = accS3[0];
        redS[w][48 + r0 + 1][mcol] = accS3[1];
        redS[w][48 + r0 + 2][mcol] = accS3[2];
        redS[w][48 + r0 + 3][mcol] = accS3[3];
    }
    redGp[w][l] = accG;
    __syncthreads();

    if (tid < 64) {   // wave 0 reduces gram
        const f32x4 g = redGp[0][l] + redGp[1][l] + redGp[2][l] + redGp[3][l];
        if (mcol < Mn) {
            if (r0 + 0 < Mn) redG[(r0 + 0) * Mn + mcol] = g[0];
            if (r0 + 1 < Mn) redG[(r0 + 1) * Mn + mcol] = g[1];
            if (r0 + 2 < Mn) redG[(r0 + 2) * Mn + mcol] = g[2];
            if (r0 + 3 < Mn) redG[(r0 + 3) * Mn + mcol] = g[3];
        }
    }
    __syncthreads();

    // finish: one thread per b
    if (tid < Bn) {
        const int b = tid;
        float wv[Mn];
        float numer = 0.f;
#pragma unroll
        for (int m = 0; m < Mn; ++m) {
            const float s = redS[0][b][m] + redS[1][b][m]
                          + redS[2][b][m] + redS[3][b][m];
            wv[m] = __expf(BETA * (s - 1.f));
            numer = fmaf(wv[m], s, numer);
        }
        float den2 = 0.f;
#pragma unroll
        for (int i = 0; i < Mn; ++i) {
            float row = 0.f;
#pragma unroll
            for (int j = 0; j < Mn; ++j) row = fmaf(wv[j], redG[i * Mn + j], row);
            den2 = fmaf(wv[i], row, den2);
        }
        out[b * Cn + c] = 100.f * numer / sqrtf(den2);
    }
}

extern "C" void kernel_launch(void* const* d_in, const int* in_sizes, int n_in,
                              void* d_out, int out_size, void* d_ws, size_t ws_size,
                              hipStream_t stream) {
    const float* img = (const float*)d_in[0];  // [64][1024] f32
    const float* mem = (const float*)d_in[1];  // [1000][11][1024] f32
    float* out = (float*)d_out;                // [64][1000] f32
    (void)in_sizes; (void)n_in; (void)out_size;

    constexpr size_t IMGP_B = (size_t)4 * 32 * 64 * 16;   // 128 KB

    if (ws_size >= IMGP_B) {
        bf16x8* imgP = (bf16x8*)d_ws;
        pack_img_kernel<<<dim3(32), dim3(256), 0, stream>>>(img, imgP);
        fused2_kernel<1><<<dim3(Cn), dim3(256), 0, stream>>>(img, imgP, mem, out);
    } else {
        fused2_kernel<0><<<dim3(Cn), dim3(256), 0, stream>>>(img, nullptr, mem, out);
    }
}

// Round 22
// 22.490 us; speedup vs baseline: 1.7408x; 1.0186x over previous
//
#include <hip/hip_runtime.h>
#include <hip/hip_bf16.h>

// DualMem fast_get_image_pred:
//   logits[b,c] = 100 * (Σ_m w_m sim_m) / sqrt(Σ_{i,j} w_i w_j G[c,i,j])
//
// Lesson ledger (22 rounds):
//  - Cost model (calibrated R17-R21, post-dicts all rounds): time ≈
//    line-touches x ~4cyc x blocks/CU. Fragment-pattern f32 wave-loads
//    touch ~22 lines; 1KB contiguous wave-loads 16 lines. Redundant reads
//    multiply the dominant term. Ladder: 57 -> 36 -> 39 -> 22.9us (R21:
//    K split across waves, mem read once/block, gram on packed regs).
//  - R21 residual: imgP (128KB) re-read by all 1000 blocks = 2048 of 3456
//    line-cycles/block. THIS round: 2 classes/block (grid 500) — A-frags
//    reused in registers for both classes; imgP line-cycles per class
//    halve. LDS 33.7KB (below the >=48KB allocator-starvation cliff, R8).
//  - Spill triggers: launch_bounds 2nd arg / non-256 blocks / >=48KB LDS /
//    escaped local arrays. Live set here ~85 (<128-144 envelope).
//  - MFMA C-layout col=lane&15, row=(lane>>4)*4+reg (verified R12/R13).
//
// Structure (2 dispatches):
//   P1 pack_img: imgP[4][32][64] bf16x8 fragments (128 KB, L2-hot).
//   K1 fused3: grid(500); block handles classes {2bx, 2bx+1}; wave w owns
//      ksteps {8w..8w+7}: packs both classes' mem fragments once, gram
//      partials ride on them, sim partials vs all 4 b-tiles' imgP (shared
//      A-frags). LDS reduce, in-block finish for both classes.

constexpr int Bn = 64;     // batch
constexpr int Cn = 1000;   // classes
constexpr int Mn = 11;     // memories per class
constexpr int Dn = 1024;   // feature dim
constexpr float BETA = 5.5f;

typedef __attribute__((ext_vector_type(8))) short bf16x8;
typedef __attribute__((ext_vector_type(4))) float f32x4;

__device__ inline short f2bf(float x) {
    union { __hip_bfloat16 h; short s; } u;
    u.h = __float2bfloat16(x);
    return u.s;
}

__device__ inline bf16x8 pack_bf16x8(const float4 a, const float4 b) {
    bf16x8 r;
    r[0] = f2bf(a.x); r[1] = f2bf(a.y); r[2] = f2bf(a.z); r[3] = f2bf(a.w);
    r[4] = f2bf(b.x); r[5] = f2bf(b.y); r[6] = f2bf(b.z); r[7] = f2bf(b.w);
    return r;
}

// ---------------- P1: imgP fragments (R18-verified) ----------------
__global__ __launch_bounds__(256) void pack_img_kernel(
    const float* __restrict__ img, bf16x8* __restrict__ imgP) {
    const int t = blockIdx.x * 256 + threadIdx.x;   // 8192 chunks
    const int l = t & 63;
    const int kstep = (t >> 6) & 31;
    const int w = t >> 11;
    const int row = w * 16 + (l & 15);
    const int kcol = kstep * 32 + (l >> 4) * 8;
    const float4 a0 = *reinterpret_cast<const float4*>(img + row * Dn + kcol);
    const float4 a1 = *reinterpret_cast<const float4*>(img + row * Dn + kcol + 4);
    imgP[t] = pack_bf16x8(a0, a1);
}

// ---------------- K1: fused, 2 classes/block, K split across waves ----------------
__global__ __launch_bounds__(256) void fused3_kernel(
    const bf16x8* __restrict__ imgP, const float* __restrict__ mem,
    float* __restrict__ out) {
    __shared__ float redS[2][4][Bn][12];   // per-class per-wave sims (24 KB)
    __shared__ f32x4 redGp[2][4][64];      // per-class per-wave gram (8 KB)
    __shared__ float redG[2][Mn * Mn];     // reduced gram (968 B)

    const int c0  = blockIdx.x * 2;        // classes c0, c0+1
    const int tid = threadIdx.x;
    const int l   = tid & 63;
    const int w   = tid >> 6;              // wave owns ksteps {8w..8w+7}
    const int rw  = l & 15;
    const int mrow = (rw < Mn) ? rw : 0;   // pad rows alias row 0
    const int kb   = (l >> 4) * 8;

    const float* mcA = mem + (size_t)(c0 + 0) * (Mn * Dn) + mrow * Dn + kb;
    const float* mcB = mem + (size_t)(c0 + 1) * (Mn * Dn) + mrow * Dn + kb;

    // class A accumulators
    f32x4 sA0 = {0.f,0.f,0.f,0.f}, sA1 = {0.f,0.f,0.f,0.f};
    f32x4 sA2 = {0.f,0.f,0.f,0.f}, sA3 = {0.f,0.f,0.f,0.f};
    f32x4 gA  = {0.f,0.f,0.f,0.f};
    // class B accumulators
    f32x4 sB0 = {0.f,0.f,0.f,0.f}, sB1 = {0.f,0.f,0.f,0.f};
    f32x4 sB2 = {0.f,0.f,0.f,0.f}, sB3 = {0.f,0.f,0.f,0.f};
    f32x4 gB  = {0.f,0.f,0.f,0.f};

#pragma unroll
    for (int j = 0; j < 8; ++j) {
        const int kstep = 8 * w + j;
        // pack both classes' mem fragments ONCE (each mem byte read once/block)
        const float4 ma0 = *reinterpret_cast<const float4*>(mcA + kstep * 32);
        const float4 ma1 = *reinterpret_cast<const float4*>(mcA + kstep * 32 + 4);
        const float4 mb0 = *reinterpret_cast<const float4*>(mcB + kstep * 32);
        const float4 mb1 = *reinterpret_cast<const float4*>(mcB + kstep * 32 + 4);
        const bf16x8 fA = pack_bf16x8(ma0, ma1);
        const bf16x8 fB = pack_bf16x8(mb0, mb1);
        gA = __builtin_amdgcn_mfma_f32_16x16x32_bf16(fA, fA, gA, 0, 0, 0);
        gB = __builtin_amdgcn_mfma_f32_16x16x32_bf16(fB, fB, gB, 0, 0, 0);
        // A-fragments shared by both classes (the amortization)
        const bf16x8* p = imgP + kstep * 64 + l;
        const bf16x8 a0 = p[0];
        const bf16x8 a1 = p[2048];
        const bf16x8 a2 = p[4096];
        const bf16x8 a3 = p[6144];
        sA0 = __builtin_amdgcn_mfma_f32_16x16x32_bf16(a0, fA, sA0, 0, 0, 0);
        sA1 = __builtin_amdgcn_mfma_f32_16x16x32_bf16(a1, fA, sA1, 0, 0, 0);
        sA2 = __builtin_amdgcn_mfma_f32_16x16x32_bf16(a2, fA, sA2, 0, 0, 0);
        sA3 = __builtin_amdgcn_mfma_f32_16x16x32_bf16(a3, fA, sA3, 0, 0, 0);
        sB0 = __builtin_amdgcn_mfma_f32_16x16x32_bf16(a0, fB, sB0, 0, 0, 0);
        sB1 = __builtin_amdgcn_mfma_f32_16x16x32_bf16(a1, fB, sB1, 0, 0, 0);
        sB2 = __builtin_amdgcn_mfma_f32_16x16x32_bf16(a2, fB, sB2, 0, 0, 0);
        sB3 = __builtin_amdgcn_mfma_f32_16x16x32_bf16(a3, fB, sB3, 0, 0, 0);
    }

    // stash partials: C layout col=l&15 (m), row=(l>>4)*4+reg (b within tile)
    const int mcol = l & 15;
    const int r0   = (l >> 4) * 4;
    if (mcol < Mn) {
#pragma unroll
        for (int q = 0; q < 4; ++q) {
            redS[0][w][ 0 + r0 + q][mcol] = sA0[q];
            redS[0][w][16 + r0 + q][mcol] = sA1[q];
            redS[0][w][32 + r0 + q][mcol] = sA2[q];
            redS[0][w][48 + r0 + q][mcol] = sA3[q];
            redS[1][w][ 0 + r0 + q][mcol] = sB0[q];
            redS[1][w][16 + r0 + q][mcol] = sB1[q];
            redS[1][w][32 + r0 + q][mcol] = sB2[q];
            redS[1][w][48 + r0 + q][mcol] = sB3[q];
        }
    }
    redGp[0][w][l] = gA;
    redGp[1][w][l] = gB;
    __syncthreads();

    // waves 0,1 reduce gram for class 0,1
    if (tid < 128) {
        const int cc = tid >> 6;       // class index (wave-uniform)
        const f32x4 g = redGp[cc][0][l] + redGp[cc][1][l]
                      + redGp[cc][2][l] + redGp[cc][3][l];
        if (mcol < Mn) {
            if (r0 + 0 < Mn) redG[cc][(r0 + 0) * Mn + mcol] = g[0];
            if (r0 + 1 < Mn) redG[cc][(r0 + 1) * Mn + mcol] = g[1];
            if (r0 + 2 < Mn) redG[cc][(r0 + 2) * Mn + mcol] = g[2];
            if (r0 + 3 < Mn) redG[cc][(r0 + 3) * Mn + mcol] = g[3];
        }
    }
    __syncthreads();

    // finish: threads 0-63 -> class 0, 64-127 -> class 1
    if (tid < 128) {
        const int cc = tid >> 6;
        const int b  = tid & 63;
        const int c  = c0 + cc;
        float wv[Mn];
        float numer = 0.f;
#pragma unroll
        for (int m = 0; m < Mn; ++m) {
            const float s = redS[cc][0][b][m] + redS[cc][1][b][m]
                          + redS[cc][2][b][m] + redS[cc][3][b][m];
            wv[m] = __expf(BETA * (s - 1.f));
            numer = fmaf(wv[m], s, numer);
        }
        float den2 = 0.f;
#pragma unroll
        for (int i = 0; i < Mn; ++i) {
            float row = 0.f;
#pragma unroll
            for (int j = 0; j < Mn; ++j)
                row = fmaf(wv[j], redG[cc][i * Mn + j], row);
            den2 = fmaf(wv[i], row, den2);
        }
        out[b * Cn + c] = 100.f * numer / sqrtf(den2);
    }
}

// ---------------- fallback: R21 single-class fused (no ws needed) ----------------
__global__ __launch_bounds__(256) void fused2_kernel(
    const float* __restrict__ img, const float* __restrict__ mem,
    float* __restrict__ out) {
    __shared__ float redS[4][Bn][12];
    __shared__ f32x4 redGp[4][64];
    __shared__ float redG[Mn * Mn];

    const int c   = blockIdx.x;
    const int tid = threadIdx.x;
    const int l   = tid & 63;
    const int w   = tid >> 6;
    const int rw  = l & 15;
    const int mrow = (rw < Mn) ? rw : 0;
    const int kb   = (l >> 4) * 8;

    const float* mc = mem + (size_t)c * (Mn * Dn) + mrow * Dn + kb;

    f32x4 accS0 = {0.f,0.f,0.f,0.f}, accS1 = {0.f,0.f,0.f,0.f};
    f32x4 accS2 = {0.f,0.f,0.f,0.f}, accS3 = {0.f,0.f,0.f,0.f};
    f32x4 accG  = {0.f,0.f,0.f,0.f};

#pragma unroll
    for (int j = 0; j < 8; ++j) {
        const int kstep = 8 * w + j;
        const float4 m0 = *reinterpret_cast<const float4*>(mc + kstep * 32);
        const float4 m1 = *reinterpret_cast<const float4*>(mc + kstep * 32 + 4);
        const bf16x8 f = pack_bf16x8(m0, m1);
        accG = __builtin_amdgcn_mfma_f32_16x16x32_bf16(f, f, accG, 0, 0, 0);
        const float* ic = img + rw * Dn + kstep * 32 + kb;
        const float4 i00 = *reinterpret_cast<const float4*>(ic);
        const float4 i01 = *reinterpret_cast<const float4*>(ic + 4);
        const float4 i10 = *reinterpret_cast<const float4*>(ic + 16 * Dn);
        const float4 i11 = *reinterpret_cast<const float4*>(ic + 16 * Dn + 4);
        const float4 i20 = *reinterpret_cast<const float4*>(ic + 32 * Dn);
        const float4 i21 = *reinterpret_cast<const float4*>(ic + 32 * Dn + 4);
        const float4 i30 = *reinterpret_cast<const float4*>(ic + 48 * Dn);
        const float4 i31 = *reinterpret_cast<const float4*>(ic + 48 * Dn + 4);
        const bf16x8 a0 = pack_bf16x8(i00, i01);
        const bf16x8 a1 = pack_bf16x8(i10, i11);
        const bf16x8 a2 = pack_bf16x8(i20, i21);
        const bf16x8 a3 = pack_bf16x8(i30, i31);
        accS0 = __builtin_amdgcn_mfma_f32_16x16x32_bf16(a0, f, accS0, 0, 0, 0);
        accS1 = __builtin_amdgcn_mfma_f32_16x16x32_bf16(a1, f, accS1, 0, 0, 0);
        accS2 = __builtin_amdgcn_mfma_f32_16x16x32_bf16(a2, f, accS2, 0, 0, 0);
        accS3 = __builtin_amdgcn_mfma_f32_16x16x32_bf16(a3, f, accS3, 0, 0, 0);
    }

    const int mcol = l & 15;
    const int r0   = (l >> 4) * 4;
    if (mcol < Mn) {
#pragma unroll
        for (int q = 0; q < 4; ++q) {
            redS[w][ 0 + r0 + q][mcol] = accS0[q];
            redS[w][16 + r0 + q][mcol] = accS1[q];
            redS[w][32 + r0 + q][mcol] = accS2[q];
            redS[w][48 + r0 + q][mcol] = accS3[q];
        }
    }
    redGp[w][l] = accG;
    __syncthreads();

    if (tid < 64) {
        const f32x4 g = redGp[0][l] + redGp[1][l] + redGp[2][l] + redGp[3][l];
        if (mcol < Mn) {
            if (r0 + 0 < Mn) redG[(r0 + 0) * Mn + mcol] = g[0];
            if (r0 + 1 < Mn) redG[(r0 + 1) * Mn + mcol] = g[1];
            if (r0 + 2 < Mn) redG[(r0 + 2) * Mn + mcol] = g[2];
            if (r0 + 3 < Mn) redG[(r0 + 3) * Mn + mcol] = g[3];
        }
    }
    __syncthreads();

    if (tid < Bn) {
        const int b = tid;
        float wv[Mn];
        float numer = 0.f;
#pragma unroll
        for (int m = 0; m < Mn; ++m) {
            const float s = redS[0][b][m] + redS[1][b][m]
                          + redS[2][b][m] + redS[3][b][m];
            wv[m] = __expf(BETA * (s - 1.f));
            numer = fmaf(wv[m], s, numer);
        }
        float den2 = 0.f;
#pragma unroll
        for (int i = 0; i < Mn; ++i) {
            float row = 0.f;
#pragma unroll
            for (int j = 0; j < Mn; ++j) row = fmaf(wv[j], redG[i * Mn + j], row);
            den2 = fmaf(wv[i], row, den2);
        }
        out[b * Cn + c] = 100.f * numer / sqrtf(den2);
    }
}

extern "C" void kernel_launch(void* const* d_in, const int* in_sizes, int n_in,
                              void* d_out, int out_size, void* d_ws, size_t ws_size,
                              hipStream_t stream) {
    const float* img = (const float*)d_in[0];  // [64][1024] f32
    const float* mem = (const float*)d_in[1];  // [1000][11][1024] f32
    float* out = (float*)d_out;                // [64][1000] f32
    (void)in_sizes; (void)n_in; (void)out_size;

    constexpr size_t IMGP_B = (size_t)4 * 32 * 64 * 16;   // 128 KB

    if (ws_size >= IMGP_B) {
        bf16x8* imgP = (bf16x8*)d_ws;
        pack_img_kernel<<<dim3(32), dim3(256), 0, stream>>>(img, imgP);
        fused3_kernel<<<dim3(Cn / 2), dim3(256), 0, stream>>>(imgP, mem, out);
    } else {
        fused2_kernel<<<dim3(Cn), dim3(256), 0, stream>>>(img, mem, out);
    }
}